// Round 6
// baseline (637.768 us; speedup 1.0000x reference)
//
#include <hip/hip_runtime.h>

// EGNN forward — fully folded + MFMA everywhere.
// Pipeline: k_prep (weight folds + nf->bf16 + agg zero) -> k_hist -> k_scanA
//   -> k_scanC -> k_scatter (u64-packed sort by row) -> k_edge -> k_node.
// ws: agg_m[N*64]f | agg_x[N*3]f | deg[N]i | WA[2048]f | WB[2048]f | WF1[2048]f
//   | Wno[4096]f | bSum[64]f | bn1f[64]f | bno[64]f | rowNext[N]i | bsumBuf[512]i
//   | srt8[E]u64 | nfb[N*32]bf16
// d_out: out[N*64] | coords_out[N*3]  (no aliasing this round)

typedef __attribute__((ext_vector_type(4))) float f32x4;
typedef __attribute__((ext_vector_type(8))) short short8;

__device__ __forceinline__ void atomAddF(float* p, float v) { unsafeAtomicAdd(p, v); }

__device__ __forceinline__ unsigned short f2bf(float f) {
  unsigned int u = __builtin_bit_cast(unsigned int, f);
  unsigned int r = (u + 0x7FFFu + ((u >> 16) & 1u)) >> 16;
  return (unsigned short)r;
}
__device__ __forceinline__ float bf2f(unsigned short s) {
  unsigned int v = ((unsigned int)s) << 16;
  return __builtin_bit_cast(float, v);
}

// ---------------- k_prep: folds + nf->bf16 + agg zero --------------------
__global__ __launch_bounds__(256) void k_prep(
    const float* __restrict__ nf, const float* __restrict__ W_in,
    const float* __restrict__ b_in, const float* __restrict__ We1,
    const float* __restrict__ be1, const float* __restrict__ Wn1,
    const float* __restrict__ bn1, const float* __restrict__ Wn2,
    const float* __restrict__ bn2, const float* __restrict__ W_out,
    const float* __restrict__ b_out, unsigned short* __restrict__ nfb,
    float* __restrict__ WA, float* __restrict__ WB, float* __restrict__ WF1,
    float* __restrict__ Wno, float* __restrict__ bSum, float* __restrict__ bn1f,
    float* __restrict__ bno, float* __restrict__ aggz, int N) {
  const int b = blockIdx.x, t = threadIdx.x;
  if (b == 0 || b == 1) {
    const float* Wsrc = (b == 0) ? We1 : (We1 + 64 * 64);
    float* dst = (b == 0) ? WA : WB;
    for (int idx = t; idx < 2048; idx += 256) {
      const int i = idx >> 6, n = idx & 63;
      float s = 0.f;
      for (int h = 0; h < 64; ++h) s = fmaf(W_in[i * 64 + h], Wsrc[h * 64 + n], s);
      dst[idx] = s;
    }
  } else if (b == 2) {
    for (int idx = t; idx < 2048; idx += 256) {
      const int i = idx >> 6, n = idx & 63;
      float s = 0.f;
      for (int h = 0; h < 64; ++h) s = fmaf(W_in[i * 64 + h], Wn1[h * 64 + n], s);
      WF1[idx] = s;
    }
    if (t < 64) {
      float s1 = bn1[t], s2 = be1[t];
      for (int h = 0; h < 64; ++h) {
        s1 = fmaf(b_in[h], Wn1[h * 64 + t], s1);
        s2 = fmaf(b_in[h], We1[h * 64 + t] + We1[(64 + h) * 64 + t], s2);
      }
      bn1f[t] = s1;
      bSum[t] = s2;
    }
  } else if (b <= 6) {
    const int base = (b - 3) * 1024;
    for (int idx = t; idx < 1024; idx += 256) {
      const int kk = (base + idx) >> 6, n = (base + idx) & 63;
      float s = 0.f;
      for (int h = 0; h < 64; ++h) s = fmaf(Wn2[kk * 64 + h], W_out[h * 64 + n], s);
      Wno[base + idx] = s;
    }
    if (b == 3 && t < 64) {
      float s = b_out[t];
      for (int h = 0; h < 64; ++h) s = fmaf(bn2[h], W_out[h * 64 + t], s);
      bno[t] = s;
    }
  } else {
    const int bid = b - 7, nb = gridDim.x - 7;
    const int tot8 = N * 8;
    for (int i = bid * 256 + t; i < tot8; i += nb * 256) {
      const f32x4 v = *reinterpret_cast<const f32x4*>(nf + (size_t)i * 4);
      ushort4 o;
      o.x = f2bf(v[0]); o.y = f2bf(v[1]); o.z = f2bf(v[2]); o.w = f2bf(v[3]);
      *reinterpret_cast<ushort4*>(nfb + (size_t)i * 4) = o;
    }
    const size_t tot = (size_t)N * 68;
    for (size_t i = (size_t)bid * 256 + t; i * 4 < tot; i += (size_t)nb * 256) {
      const size_t off = i * 4;
      if (off + 4 <= tot)
        *reinterpret_cast<float4*>(aggz + off) = make_float4(0.f, 0.f, 0.f, 0.f);
      else
        for (size_t q = off; q < tot; ++q) aggz[q] = 0.f;
    }
  }
}

// ---------------- sort pipeline ----------------
__global__ __launch_bounds__(256) void k_hist(const int* __restrict__ eidx,
                                              int* __restrict__ deg, int E) {
  for (int e = blockIdx.x * 256 + threadIdx.x; e < E; e += gridDim.x * 256)
    atomicAdd(&deg[eidx[e]], 1);
}

__global__ __launch_bounds__(256) void k_scanA(const int* __restrict__ deg,
                                               int* __restrict__ excl,
                                               int* __restrict__ bsum, int N) {
  __shared__ int s[256];
  const int t = threadIdx.x;
  const int i = blockIdx.x * 256 + t;
  const int v = (i < N) ? deg[i] : 0;
  s[t] = v;
  __syncthreads();
#pragma unroll
  for (int off = 1; off < 256; off <<= 1) {
    int x = 0;
    if (t >= off) x = s[t - off];
    __syncthreads();
    s[t] += x;
    __syncthreads();
  }
  if (i < N) excl[i] = s[t] - v;
  if (t == 255) bsum[blockIdx.x] = s[255];
}

__global__ __launch_bounds__(256) void k_scanC(int* __restrict__ excl,
                                               const int* __restrict__ bsum,
                                               int N) {
  __shared__ int sh[256];
  const int t = threadIdx.x, b = blockIdx.x;
  int part = 0;
  for (int i = t; i < b; i += 256) part += bsum[i];
  sh[t] = part;
  __syncthreads();
#pragma unroll
  for (int off = 128; off; off >>= 1) {
    if (t < off) sh[t] += sh[t + off];
    __syncthreads();
  }
  const int add = sh[0];
  const int i = b * 256 + t;
  if (i < N) excl[i] += add;
}

__global__ __launch_bounds__(256) void k_scatter(
    const int* __restrict__ eidx, int* __restrict__ rowNext,
    unsigned long long* __restrict__ srt8, int E) {
  for (int e = blockIdx.x * 256 + threadIdx.x; e < E; e += gridDim.x * 256) {
    const int r = eidx[e];
    const int c = eidx[E + e];
    const int pos = atomicAdd(&rowNext[r], 1);
    srt8[pos] = (unsigned long long)r | ((unsigned long long)c << 18) |
                ((unsigned long long)e << 36);
  }
}

// ---------------- k_edge ----------------
struct EdgeLds {
  unsigned short We2t[4096];     // [n][k] stride 64, XOR-swizzled
  unsigned short Wc1t[4096];
  unsigned short WeaP[64 * 24];  // [n][24]: k<16 ea wts, k==16 radial wt
  unsigned short x[4][32 * 64];  // per-wave tile, stride 64, XOR-swizzled
  float cd[4][32 * 4];           // dx,dy,dz,(radial -> s)
  int4 idx4[4][32];              // (row, col, perm, 0)
};

__global__ __launch_bounds__(256, 4) void k_edge(
    const unsigned short* __restrict__ nfb, const float* __restrict__ ea,
    const float* __restrict__ co, const unsigned long long* __restrict__ srt8,
    const float* __restrict__ We1, const float* __restrict__ WA,
    const float* __restrict__ WB, const float* __restrict__ bSum,
    const float* __restrict__ be2, const float* __restrict__ We2,
    const float* __restrict__ bc1, const float* __restrict__ Wc1,
    const float* __restrict__ Wc2, const float* __restrict__ bc2,
    float* __restrict__ agg_m, float* __restrict__ agg_x, int E) {
  __shared__ EdgeLds S;
  const int tid = threadIdx.x;
  for (int i = tid; i < 4096; i += 256) {
    const int k = i >> 6, n = i & 63;
    const int byt = n * 128 + ((k * 2) ^ ((n & 7) << 4));
    *reinterpret_cast<unsigned short*>(reinterpret_cast<char*>(S.We2t) + byt) =
        f2bf(We2[k * 64 + n]);
    *reinterpret_cast<unsigned short*>(reinterpret_cast<char*>(S.Wc1t) + byt) =
        f2bf(Wc1[k * 64 + n]);
  }
  for (int i = tid; i < 64 * 24; i += 256) {
    const int n = i / 24, k = i - n * 24;
    const float v = (k < 16) ? We1[(129 + k) * 64 + n]
                             : ((k == 16) ? We1[128 * 64 + n] : 0.f);
    S.WeaP[n * 24 + k] = f2bf(v);
  }
  __syncthreads();

  const int w = tid >> 6, lane = tid & 63;
  const int g = lane >> 4, t = lane & 15;
  const float bc2v = bc2[0];

  // persistent register B-fragments for WA/WB
  short8 fWA[4], fWB[4];
  float bS_r[4], be2_r[4], bc1_r[4], wc2_r[4];
#pragma unroll
  for (int nt = 0; nt < 4; ++nt) {
    const int n = t + 16 * nt;
    short8 a, b;
#pragma unroll
    for (int j = 0; j < 8; ++j) {
      a[j] = (short)f2bf(WA[(g * 8 + j) * 64 + n]);
      b[j] = (short)f2bf(WB[(g * 8 + j) * 64 + n]);
    }
    fWA[nt] = a;
    fWB[nt] = b;
    bS_r[nt] = bSum[n];
    be2_r[nt] = be2[n];
    bc1_r[nt] = bc1[n];
    wc2_r[nt] = Wc2[n];
  }

  char* xb = reinterpret_cast<char*>(&S.x[w][0]);
  float* cdw = &S.cd[w][0];
  int4* idxw = &S.idx4[w][0];
  const int ngroups = (E + 31) >> 5;
  const int GS = gridDim.x * 4;

  int grp = blockIdx.x * 4 + w;
  unsigned long long s8 = 0;
  if (grp < ngroups && lane < 32) {
    int e = grp * 32 + lane;
    if (e >= E) e = E - 1;
    s8 = srt8[e];
  }

  for (; grp < ngroups; grp += GS) {
    const int e0 = grp * 32;
    // decode + publish indices, coords, radial
    if (lane < 32) {
      const int r = (int)(s8 & 0x3FFFFull);
      const int c = (int)((s8 >> 18) & 0x3FFFFull);
      const int p = (int)(s8 >> 36);
      idxw[lane] = make_int4(r, c, p, 0);
      const float rx = co[(size_t)r * 3 + 0], ry = co[(size_t)r * 3 + 1],
                  rz = co[(size_t)r * 3 + 2];
      const float cx = co[(size_t)c * 3 + 0], cy = co[(size_t)c * 3 + 1],
                  cz = co[(size_t)c * 3 + 2];
      const float dx = rx - cx, dy = ry - cy, dz = rz - cz;
      f32x4 c4;
      c4[0] = dx; c4[1] = dy; c4[2] = dz; c4[3] = dx * dx + dy * dy + dz * dz;
      *reinterpret_cast<f32x4*>(&cdw[lane * 4]) = c4;
    }
    // prefetch next group's srt8
    {
      const int gn = grp + GS;
      if (lane < 32) {
        long e = (long)gn * 32 + lane;
        if (e >= E) e = E - 1;
        s8 = srt8[e];
      }
    }
    // fragment sources
    short8 Ar[2], Ac[2], Ae[2];
#pragma unroll
    for (int mt = 0; mt < 2; ++mt) {
      const int4 v = idxw[t + 16 * mt];
      Ar[mt] = *reinterpret_cast<const short8*>(nfb + (size_t)v.x * 32 + g * 8);
      Ac[mt] = *reinterpret_cast<const short8*>(nfb + (size_t)v.y * 32 + g * 8);
      short8 a = {};
      if (g < 2) {
        const f32x4 x0 = *reinterpret_cast<const f32x4*>(ea + (size_t)v.z * 16 + g * 8);
        const f32x4 x1 = *reinterpret_cast<const f32x4*>(ea + (size_t)v.z * 16 + g * 8 + 4);
#pragma unroll
        for (int j = 0; j < 4; ++j) {
          a[j] = (short)f2bf(x0[j]);
          a[4 + j] = (short)f2bf(x1[j]);
        }
      } else if (g == 2) {
        a[0] = (short)f2bf(cdw[(t + 16 * mt) * 4 + 3]);
      }
      Ae[mt] = a;
    }
    // ---- layer 1: acc = bSum + nf_r@WA + nf_c@WB + ea@Wea ----
    f32x4 acc[2][4];
#pragma unroll
    for (int mt = 0; mt < 2; ++mt)
#pragma unroll
      for (int nt = 0; nt < 4; ++nt) {
        f32x4 c;
        c[0] = bS_r[nt]; c[1] = bS_r[nt]; c[2] = bS_r[nt]; c[3] = bS_r[nt];
        acc[mt][nt] = c;
      }
#pragma unroll
    for (int nt = 0; nt < 4; ++nt) {
      const int n = t + 16 * nt;
      short8 be = {};
      if (g < 2)
        be = *reinterpret_cast<const short8*>(&S.WeaP[n * 24 + g * 8]);
      else if (g == 2)
        be[0] = (short)S.WeaP[n * 24 + 16];
#pragma unroll
      for (int mt = 0; mt < 2; ++mt) {
        acc[mt][nt] = __builtin_amdgcn_mfma_f32_16x16x32_bf16(Ar[mt], fWA[nt], acc[mt][nt], 0, 0, 0);
        acc[mt][nt] = __builtin_amdgcn_mfma_f32_16x16x32_bf16(Ac[mt], fWB[nt], acc[mt][nt], 0, 0, 0);
        acc[mt][nt] = __builtin_amdgcn_mfma_f32_16x16x32_bf16(Ae[mt], be, acc[mt][nt], 0, 0, 0);
      }
    }
    // relu -> t1 (swizzled bf16 store)
#pragma unroll
    for (int mt = 0; mt < 2; ++mt)
#pragma unroll
      for (int nt = 0; nt < 4; ++nt)
#pragma unroll
        for (int j = 0; j < 4; ++j) {
          const int row = g * 4 + j + 16 * mt, col = t + 16 * nt;
          *reinterpret_cast<unsigned short*>(
              xb + row * 128 + ((col * 2) ^ ((row & 7) << 4))) =
              f2bf(fmaxf(acc[mt][nt][j], 0.f));
        }
    // ---- layer 2: m = relu(t1 @ We2 + be2) ----
    short8 A2[2][2];
#pragma unroll
    for (int mt = 0; mt < 2; ++mt)
#pragma unroll
      for (int kt = 0; kt < 2; ++kt) {
        const int row = t + 16 * mt;
        A2[mt][kt] = *reinterpret_cast<const short8*>(
            xb + row * 128 + ((kt * 64 + g * 16) ^ ((row & 7) << 4)));
      }
    f32x4 m2[2][4];
#pragma unroll
    for (int mt = 0; mt < 2; ++mt)
#pragma unroll
      for (int nt = 0; nt < 4; ++nt) {
        const int n = t + 16 * nt;
        f32x4 c;
        c[0] = be2_r[nt]; c[1] = be2_r[nt]; c[2] = be2_r[nt]; c[3] = be2_r[nt];
#pragma unroll
        for (int kt = 0; kt < 2; ++kt) {
          const short8 b = *reinterpret_cast<const short8*>(
              reinterpret_cast<char*>(S.We2t) + n * 128 +
              ((kt * 64 + g * 16) ^ ((n & 7) << 4)));
          c = __builtin_amdgcn_mfma_f32_16x16x32_bf16(A2[mt][kt], b, c, 0, 0, 0);
        }
#pragma unroll
        for (int j = 0; j < 4; ++j) c[j] = fmaxf(c[j], 0.f);
        m2[mt][nt] = c;
      }
    // m -> x (swizzled)
#pragma unroll
    for (int mt = 0; mt < 2; ++mt)
#pragma unroll
      for (int nt = 0; nt < 4; ++nt)
#pragma unroll
        for (int j = 0; j < 4; ++j) {
          const int row = g * 4 + j + 16 * mt, col = t + 16 * nt;
          *reinterpret_cast<unsigned short*>(
              xb + row * 128 + ((col * 2) ^ ((row & 7) << 4))) =
              f2bf(m2[mt][nt][j]);
        }
    // ---- coord MLP: p = relu(m @ Wc1 + bc1); s = p.Wc2 + bc2 ----
    short8 A3[2][2];
#pragma unroll
    for (int mt = 0; mt < 2; ++mt)
#pragma unroll
      for (int kt = 0; kt < 2; ++kt) {
        const int row = t + 16 * mt;
        A3[mt][kt] = *reinterpret_cast<const short8*>(
            xb + row * 128 + ((kt * 64 + g * 16) ^ ((row & 7) << 4)));
      }
    float sv[2][4];
#pragma unroll
    for (int mt = 0; mt < 2; ++mt)
#pragma unroll
      for (int j = 0; j < 4; ++j) sv[mt][j] = 0.f;
#pragma unroll
    for (int mt = 0; mt < 2; ++mt)
#pragma unroll
      for (int nt = 0; nt < 4; ++nt) {
        const int n = t + 16 * nt;
        f32x4 c;
        c[0] = bc1_r[nt]; c[1] = bc1_r[nt]; c[2] = bc1_r[nt]; c[3] = bc1_r[nt];
#pragma unroll
        for (int kt = 0; kt < 2; ++kt) {
          const short8 b = *reinterpret_cast<const short8*>(
              reinterpret_cast<char*>(S.Wc1t) + n * 128 +
              ((kt * 64 + g * 16) ^ ((n & 7) << 4)));
          c = __builtin_amdgcn_mfma_f32_16x16x32_bf16(A3[mt][kt], b, c, 0, 0, 0);
        }
#pragma unroll
        for (int j = 0; j < 4; ++j) sv[mt][j] = fmaf(fmaxf(c[j], 0.f), wc2_r[nt], sv[mt][j]);
      }
#pragma unroll
    for (int d = 1; d < 16; d <<= 1)
#pragma unroll
      for (int mt = 0; mt < 2; ++mt)
#pragma unroll
        for (int j = 0; j < 4; ++j) sv[mt][j] += __shfl_xor(sv[mt][j], d, 64);
#pragma unroll
    for (int mt = 0; mt < 2; ++mt)
#pragma unroll
      for (int j = 0; j < 4; ++j) sv[mt][j] += bc2v;
    // stash s per row (radial slot; radial already consumed)
#pragma unroll
    for (int mt = 0; mt < 2; ++mt)
#pragma unroll
      for (int j = 0; j < 4; ++j)
        if (t == 0) cdw[(g * 4 + j + 16 * mt) * 4 + 3] = sv[mt][j];

    // ---- run-compressed agg_m (lane owns column `lane`) ----
    {
      float accm = 0.f;
#pragma unroll
      for (int r = 0; r < 32; ++r) {
        const int rIr = idxw[r].x;
        const bool valid = (e0 + r) < E;
        const float mv = bf2f(*reinterpret_cast<const unsigned short*>(
            xb + r * 128 + ((lane * 2) ^ ((r & 7) << 4))));
        if (valid) accm += mv;
        const bool closes = (r == 31) || ((e0 + r + 1) >= E) || (idxw[r + 1].x != rIr);
        if (valid && closes) {
          atomAddF(&agg_m[(size_t)rIr * 64 + lane], accm);
          accm = 0.f;
        }
      }
    }
    // ---- run-compressed agg_x (lanes 0..2) ----
    if (lane < 3) {
      float accx = 0.f;
#pragma unroll
      for (int r = 0; r < 32; ++r) {
        const int rIr = idxw[r].x;
        const bool valid = (e0 + r) < E;
        if (valid) accx += cdw[r * 4 + lane] * cdw[r * 4 + 3];
        const bool closes = (r == 31) || ((e0 + r + 1) >= E) || (idxw[r + 1].x != rIr);
        if (valid && closes) {
          atomAddF(&agg_x[(size_t)rIr * 3 + lane], accx);
          accx = 0.f;
        }
      }
    }
  }
}

// ---------------- k_node (MFMA, folded weights) ----------------
struct NodeLds {
  unsigned short Wn1bT[64 * 72];  // [n][k] stride 72 (agg-part of Wn1)
  unsigned short WnoT[64 * 72];   // [n][k] stride 72 (Wn2@W_out fold)
  unsigned short x[4][32 * 72];   // q tile
};

__global__ __launch_bounds__(256, 4) void k_node(
    const unsigned short* __restrict__ nfb, const float* __restrict__ agg_m,
    const float* __restrict__ agg_x, const int* __restrict__ deg,
    const float* __restrict__ co, const float* __restrict__ WF1,
    const float* __restrict__ Wn1, const float* __restrict__ Wno,
    const float* __restrict__ bn1f, const float* __restrict__ bno,
    float* __restrict__ out, float* __restrict__ co_out, int N) {
  __shared__ NodeLds S;
  const int tid = threadIdx.x;
  for (int i = tid; i < 4096; i += 256) {
    const int k = i >> 6, n = i & 63;
    S.Wn1bT[n * 72 + k] = f2bf(Wn1[(64 + k) * 64 + n]);
    S.WnoT[n * 72 + k] = f2bf(Wno[k * 64 + n]);
  }
  __syncthreads();
  const int w = tid >> 6, lane = tid & 63;
  const int g = lane >> 4, t = lane & 15;

  short8 fW1[4];
  float b1_r[4], bo_r[4];
#pragma unroll
  for (int nt = 0; nt < 4; ++nt) {
    const int n = t + 16 * nt;
    short8 a;
#pragma unroll
    for (int j = 0; j < 8; ++j) a[j] = (short)f2bf(WF1[(g * 8 + j) * 64 + n]);
    fW1[nt] = a;
    b1_r[nt] = bn1f[n];
    bo_r[nt] = bno[n];
  }

  unsigned short* xw = &S.x[w][0];
  const int ngroups = (N + 31) >> 5;
  const int GS = gridDim.x * 4;

  for (int grp = blockIdx.x * 4 + w; grp < ngroups; grp += GS) {
    const int base = grp * 32;
    short8 A1[2], Aa[2][2];
#pragma unroll
    for (int mt = 0; mt < 2; ++mt) {
      int node = base + t + 16 * mt;
      if (node >= N) node = N - 1;
      A1[mt] = *reinterpret_cast<const short8*>(nfb + (size_t)node * 32 + g * 8);
#pragma unroll
      for (int kt = 0; kt < 2; ++kt) {
        const f32x4 v0 = *reinterpret_cast<const f32x4*>(
            agg_m + (size_t)node * 64 + kt * 32 + g * 8);
        const f32x4 v1 = *reinterpret_cast<const f32x4*>(
            agg_m + (size_t)node * 64 + kt * 32 + g * 8 + 4);
        short8 a;
#pragma unroll
        for (int j = 0; j < 4; ++j) {
          a[j] = (short)f2bf(v0[j]);
          a[4 + j] = (short)f2bf(v1[j]);
        }
        Aa[mt][kt] = a;
      }
    }
    // layer 1
    f32x4 acc[2][4];
#pragma unroll
    for (int mt = 0; mt < 2; ++mt)
#pragma unroll
      for (int nt = 0; nt < 4; ++nt) {
        const int n = t + 16 * nt;
        f32x4 c;
        c[0] = b1_r[nt]; c[1] = b1_r[nt]; c[2] = b1_r[nt]; c[3] = b1_r[nt];
        c = __builtin_amdgcn_mfma_f32_16x16x32_bf16(A1[mt], fW1[nt], c, 0, 0, 0);
#pragma unroll
        for (int kt = 0; kt < 2; ++kt) {
          const short8 b = *reinterpret_cast<const short8*>(
              &S.Wn1bT[n * 72 + kt * 32 + g * 8]);
          c = __builtin_amdgcn_mfma_f32_16x16x32_bf16(Aa[mt][kt], b, c, 0, 0, 0);
        }
        acc[mt][nt] = c;
      }
    // relu -> q
#pragma unroll
    for (int mt = 0; mt < 2; ++mt)
#pragma unroll
      for (int nt = 0; nt < 4; ++nt)
#pragma unroll
        for (int j = 0; j < 4; ++j)
          xw[(g * 4 + j + 16 * mt) * 72 + t + 16 * nt] =
              f2bf(fmaxf(acc[mt][nt][j], 0.f));
    // layer 2 (folded) -> out
    short8 A2[2][2];
#pragma unroll
    for (int mt = 0; mt < 2; ++mt)
#pragma unroll
      for (int kt = 0; kt < 2; ++kt)
        A2[mt][kt] = *reinterpret_cast<const short8*>(
            &xw[(t + 16 * mt) * 72 + kt * 32 + g * 8]);
#pragma unroll
    for (int mt = 0; mt < 2; ++mt)
#pragma unroll
      for (int nt = 0; nt < 4; ++nt) {
        const int n = t + 16 * nt;
        f32x4 c;
        c[0] = bo_r[nt]; c[1] = bo_r[nt]; c[2] = bo_r[nt]; c[3] = bo_r[nt];
#pragma unroll
        for (int kt = 0; kt < 2; ++kt) {
          const short8 b = *reinterpret_cast<const short8*>(
              &S.WnoT[n * 72 + kt * 32 + g * 8]);
          c = __builtin_amdgcn_mfma_f32_16x16x32_bf16(A2[mt][kt], b, c, 0, 0, 0);
        }
#pragma unroll
        for (int j = 0; j < 4; ++j) {
          const int node = base + g * 4 + j + 16 * mt;
          if (node < N) out[(size_t)node * 64 + n] = c[j];
        }
      }
    // coords update
    if (lane < 32) {
      const int node = base + lane;
      if (node < N) {
        const float dv = fmaxf((float)deg[node], 1.f);
#pragma unroll
        for (int d = 0; d < 3; ++d)
          co_out[(size_t)node * 3 + d] =
              co[(size_t)node * 3 + d] + agg_x[(size_t)node * 3 + d] / dv;
      }
    }
  }
}

extern "C" void kernel_launch(void* const* d_in, const int* in_sizes, int n_in,
                              void* d_out, int out_size, void* d_ws, size_t ws_size,
                              hipStream_t stream) {
  const float* nf = (const float*)d_in[0];
  const float* ea = (const float*)d_in[1];
  const float* co = (const float*)d_in[2];
  const int* ei = (const int*)d_in[3];
  const float* W_in = (const float*)d_in[4];
  const float* b_in = (const float*)d_in[5];
  const float* W_out = (const float*)d_in[6];
  const float* b_out = (const float*)d_in[7];
  const float* We1 = (const float*)d_in[8];
  const float* be1 = (const float*)d_in[9];
  const float* We2 = (const float*)d_in[10];
  const float* be2 = (const float*)d_in[11];
  const float* Wn1 = (const float*)d_in[12];
  const float* bn1 = (const float*)d_in[13];
  const float* Wn2 = (const float*)d_in[14];
  const float* bn2 = (const float*)d_in[15];
  const float* Wc1 = (const float*)d_in[16];
  const float* bc1 = (const float*)d_in[17];
  const float* Wc2 = (const float*)d_in[18];
  const float* bc2 = (const float*)d_in[19];

  const int N = in_sizes[0] / 32;
  const int E = in_sizes[1] / 16;

  float* ws = (float*)d_ws;
  float* agg_m = ws;                                   // N*64
  float* agg_x = agg_m + (size_t)N * 64;               // N*3
  int* deg = (int*)(agg_x + (size_t)N * 3);            // N
  float* WA = (float*)(deg + N);                       // 2048
  float* WB = WA + 2048;
  float* WF1 = WB + 2048;
  float* Wno = WF1 + 2048;                             // 4096
  float* bSum = Wno + 4096;                            // 64
  float* bn1f = bSum + 64;
  float* bno = bn1f + 64;
  int* rowNext = (int*)(bno + 64);                     // N
  int* bsumBuf = rowNext + N;                          // 512
  // 8B-align srt8
  uintptr_t pp = (uintptr_t)(bsumBuf + 512);
  pp = (pp + 7) & ~(uintptr_t)7;
  unsigned long long* srt8 = (unsigned long long*)pp;  // E
  unsigned short* nfb = (unsigned short*)(srt8 + E);   // N*32

  float* outp = (float*)d_out;
  float* co_out = outp + (size_t)N * 64;

  const int nb = (N + 255) / 256;

  k_prep<<<1031, 256, 0, stream>>>(nf, W_in, b_in, We1, be1, Wn1, bn1, Wn2,
                                   bn2, W_out, b_out, nfb, WA, WB, WF1, Wno,
                                   bSum, bn1f, bno, agg_m, N);
  k_hist<<<512, 256, 0, stream>>>(ei, deg, E);
  k_scanA<<<nb, 256, 0, stream>>>(deg, rowNext, bsumBuf, N);
  k_scanC<<<nb, 256, 0, stream>>>(rowNext, bsumBuf, N);
  k_scatter<<<512, 256, 0, stream>>>(ei, rowNext, srt8, E);
  k_edge<<<1024, 256, 0, stream>>>(nfb, ea, co, srt8, We1, WA, WB, bSum, be2,
                                   We2, bc1, Wc1, Wc2, bc2, agg_m, agg_x, E);
  k_node<<<512, 256, 0, stream>>>(nfb, agg_m, agg_x, deg, co, WF1, Wn1, Wno,
                                  bn1f, bno, outp, co_out, N);
}

// Round 7
// 495.528 us; speedup vs baseline: 1.2870x; 1.2870x over previous
//
#include <hip/hip_runtime.h>

// EGNN forward — fully folded + MFMA everywhere.
// Pipeline: k_prep (weight folds + nf->bf16 + agg zero) -> k_hist -> k_scanA
//   -> k_scanC -> k_scatter (u64-packed sort by row) -> k_edge -> k_node.
// ws: agg_m[N*64]f | agg_x[N*3]f | deg[N]i | WA[2048]f | WB[2048]f | WF1[2048]f
//   | Wno[4096]f | bSum[64]f | bn1f[64]f | bno[64]f | rowNext[N]i | bsumBuf[512]i
//   | srt8[E]u64 | nfb[N*32]bf16
// d_out: out[N*64] | coords_out[N*3]
//
// Round-6 lesson: __launch_bounds__(256,4) + persistent B-fragments => VGPR
// cap too low => spills (VGPR=64, WRITE_SIZE 6x). This round: bounds(256,3),
// WA/WB fragments staged in LDS, no large persistent register arrays.

typedef __attribute__((ext_vector_type(4))) float f32x4;
typedef __attribute__((ext_vector_type(8))) short short8;

__device__ __forceinline__ void atomAddF(float* p, float v) { unsafeAtomicAdd(p, v); }

__device__ __forceinline__ unsigned short f2bf(float f) {
  unsigned int u = __builtin_bit_cast(unsigned int, f);
  unsigned int r = (u + 0x7FFFu + ((u >> 16) & 1u)) >> 16;
  return (unsigned short)r;
}
__device__ __forceinline__ float bf2f(unsigned short s) {
  unsigned int v = ((unsigned int)s) << 16;
  return __builtin_bit_cast(float, v);
}

// ---------------- k_prep: folds + nf->bf16 + agg zero --------------------
__global__ __launch_bounds__(256) void k_prep(
    const float* __restrict__ nf, const float* __restrict__ W_in,
    const float* __restrict__ b_in, const float* __restrict__ We1,
    const float* __restrict__ be1, const float* __restrict__ Wn1,
    const float* __restrict__ bn1, const float* __restrict__ Wn2,
    const float* __restrict__ bn2, const float* __restrict__ W_out,
    const float* __restrict__ b_out, unsigned short* __restrict__ nfb,
    float* __restrict__ WA, float* __restrict__ WB, float* __restrict__ WF1,
    float* __restrict__ Wno, float* __restrict__ bSum, float* __restrict__ bn1f,
    float* __restrict__ bno, float* __restrict__ aggz, int N) {
  const int b = blockIdx.x, t = threadIdx.x;
  if (b == 0 || b == 1) {
    const float* Wsrc = (b == 0) ? We1 : (We1 + 64 * 64);
    float* dst = (b == 0) ? WA : WB;
    for (int idx = t; idx < 2048; idx += 256) {
      const int i = idx >> 6, n = idx & 63;
      float s = 0.f;
      for (int h = 0; h < 64; ++h) s = fmaf(W_in[i * 64 + h], Wsrc[h * 64 + n], s);
      dst[idx] = s;
    }
  } else if (b == 2) {
    for (int idx = t; idx < 2048; idx += 256) {
      const int i = idx >> 6, n = idx & 63;
      float s = 0.f;
      for (int h = 0; h < 64; ++h) s = fmaf(W_in[i * 64 + h], Wn1[h * 64 + n], s);
      WF1[idx] = s;
    }
    if (t < 64) {
      float s1 = bn1[t], s2 = be1[t];
      for (int h = 0; h < 64; ++h) {
        s1 = fmaf(b_in[h], Wn1[h * 64 + t], s1);
        s2 = fmaf(b_in[h], We1[h * 64 + t] + We1[(64 + h) * 64 + t], s2);
      }
      bn1f[t] = s1;
      bSum[t] = s2;
    }
  } else if (b <= 6) {
    const int base = (b - 3) * 1024;
    for (int idx = t; idx < 1024; idx += 256) {
      const int kk = (base + idx) >> 6, n = (base + idx) & 63;
      float s = 0.f;
      for (int h = 0; h < 64; ++h) s = fmaf(Wn2[kk * 64 + h], W_out[h * 64 + n], s);
      Wno[base + idx] = s;
    }
    if (b == 3 && t < 64) {
      float s = b_out[t];
      for (int h = 0; h < 64; ++h) s = fmaf(bn2[h], W_out[h * 64 + t], s);
      bno[t] = s;
    }
  } else {
    const int bid = b - 7, nb = gridDim.x - 7;
    const int tot8 = N * 8;
    for (int i = bid * 256 + t; i < tot8; i += nb * 256) {
      const f32x4 v = *reinterpret_cast<const f32x4*>(nf + (size_t)i * 4);
      ushort4 o;
      o.x = f2bf(v[0]); o.y = f2bf(v[1]); o.z = f2bf(v[2]); o.w = f2bf(v[3]);
      *reinterpret_cast<ushort4*>(nfb + (size_t)i * 4) = o;
    }
    const size_t tot = (size_t)N * 68;
    for (size_t i = (size_t)bid * 256 + t; i * 4 < tot; i += (size_t)nb * 256) {
      const size_t off = i * 4;
      if (off + 4 <= tot)
        *reinterpret_cast<float4*>(aggz + off) = make_float4(0.f, 0.f, 0.f, 0.f);
      else
        for (size_t q = off; q < tot; ++q) aggz[q] = 0.f;
    }
  }
}

// ---------------- sort pipeline ----------------
__global__ __launch_bounds__(256) void k_hist(const int* __restrict__ eidx,
                                              int* __restrict__ deg, int E) {
  for (int e = blockIdx.x * 256 + threadIdx.x; e < E; e += gridDim.x * 256)
    atomicAdd(&deg[eidx[e]], 1);
}

__global__ __launch_bounds__(256) void k_scanA(const int* __restrict__ deg,
                                               int* __restrict__ excl,
                                               int* __restrict__ bsum, int N) {
  __shared__ int s[256];
  const int t = threadIdx.x;
  const int i = blockIdx.x * 256 + t;
  const int v = (i < N) ? deg[i] : 0;
  s[t] = v;
  __syncthreads();
#pragma unroll
  for (int off = 1; off < 256; off <<= 1) {
    int x = 0;
    if (t >= off) x = s[t - off];
    __syncthreads();
    s[t] += x;
    __syncthreads();
  }
  if (i < N) excl[i] = s[t] - v;
  if (t == 255) bsum[blockIdx.x] = s[255];
}

__global__ __launch_bounds__(256) void k_scanC(int* __restrict__ excl,
                                               const int* __restrict__ bsum,
                                               int N) {
  __shared__ int sh[256];
  const int t = threadIdx.x, b = blockIdx.x;
  int part = 0;
  for (int i = t; i < b; i += 256) part += bsum[i];
  sh[t] = part;
  __syncthreads();
#pragma unroll
  for (int off = 128; off; off >>= 1) {
    if (t < off) sh[t] += sh[t + off];
    __syncthreads();
  }
  const int add = sh[0];
  const int i = b * 256 + t;
  if (i < N) excl[i] += add;
}

__global__ __launch_bounds__(256) void k_scatter(
    const int* __restrict__ eidx, int* __restrict__ rowNext,
    unsigned long long* __restrict__ srt8, int E) {
  for (int e = blockIdx.x * 256 + threadIdx.x; e < E; e += gridDim.x * 256) {
    const int r = eidx[e];
    const int c = eidx[E + e];
    const int pos = atomicAdd(&rowNext[r], 1);
    srt8[pos] = (unsigned long long)r | ((unsigned long long)c << 18) |
                ((unsigned long long)e << 36);
  }
}

// ---------------- k_edge ----------------
struct EdgeLds {
  unsigned short We2t[4096];     // [n][k] stride 64, XOR-swizzled
  unsigned short Wc1t[4096];
  unsigned short WAt[2048];      // [n][k] stride 32 (bank-uniform b128 reads)
  unsigned short WBt[2048];
  unsigned short WeaP[64 * 24];  // [n][24]: k<16 ea wts, k==16 radial wt
  unsigned short x[4][32 * 64];  // per-wave tile, stride 64, XOR-swizzled
  float cd[4][32 * 4];           // dx,dy,dz,(radial -> s)
  int4 idx4[4][32];              // (row, col, perm, 0)
};

__global__ __launch_bounds__(256, 3) void k_edge(
    const unsigned short* __restrict__ nfb, const float* __restrict__ ea,
    const float* __restrict__ co, const unsigned long long* __restrict__ srt8,
    const float* __restrict__ We1, const float* __restrict__ WA,
    const float* __restrict__ WB, const float* __restrict__ bSum,
    const float* __restrict__ be2, const float* __restrict__ We2,
    const float* __restrict__ bc1, const float* __restrict__ Wc1,
    const float* __restrict__ Wc2, const float* __restrict__ bc2,
    float* __restrict__ agg_m, float* __restrict__ agg_x, int E) {
  __shared__ EdgeLds S;
  const int tid = threadIdx.x;
  for (int i = tid; i < 4096; i += 256) {
    const int k = i >> 6, n = i & 63;
    const int byt = n * 128 + ((k * 2) ^ ((n & 7) << 4));
    *reinterpret_cast<unsigned short*>(reinterpret_cast<char*>(S.We2t) + byt) =
        f2bf(We2[k * 64 + n]);
    *reinterpret_cast<unsigned short*>(reinterpret_cast<char*>(S.Wc1t) + byt) =
        f2bf(Wc1[k * 64 + n]);
  }
  for (int i = tid; i < 2048; i += 256) {
    const int n = i >> 5, k = i & 31;
    S.WAt[i] = f2bf(WA[k * 64 + n]);
    S.WBt[i] = f2bf(WB[k * 64 + n]);
  }
  for (int i = tid; i < 64 * 24; i += 256) {
    const int n = i / 24, k = i - n * 24;
    const float v = (k < 16) ? We1[(129 + k) * 64 + n]
                             : ((k == 16) ? We1[128 * 64 + n] : 0.f);
    S.WeaP[n * 24 + k] = f2bf(v);
  }
  __syncthreads();

  const int w = tid >> 6, lane = tid & 63;
  const int g = lane >> 4, t = lane & 15;
  const float bc2v = bc2[0];

  float bS_r[4], be2_r[4], bc1_r[4], wc2_r[4];
#pragma unroll
  for (int nt = 0; nt < 4; ++nt) {
    const int n = t + 16 * nt;
    bS_r[nt] = bSum[n];
    be2_r[nt] = be2[n];
    bc1_r[nt] = bc1[n];
    wc2_r[nt] = Wc2[n];
  }

  char* xb = reinterpret_cast<char*>(&S.x[w][0]);
  float* cdw = &S.cd[w][0];
  int4* idxw = &S.idx4[w][0];
  const int ngroups = (E + 31) >> 5;
  const int GS = gridDim.x * 4;

  int grp = blockIdx.x * 4 + w;
  unsigned long long s8 = 0;
  if (grp < ngroups && lane < 32) {
    int e = grp * 32 + lane;
    if (e >= E) e = E - 1;
    s8 = srt8[e];
  }

  for (; grp < ngroups; grp += GS) {
    const int e0 = grp * 32;
    // decode + publish indices, coords, radial
    if (lane < 32) {
      const int r = (int)(s8 & 0x3FFFFull);
      const int c = (int)((s8 >> 18) & 0x3FFFFull);
      const int p = (int)(s8 >> 36);
      idxw[lane] = make_int4(r, c, p, 0);
      const float rx = co[(size_t)r * 3 + 0], ry = co[(size_t)r * 3 + 1],
                  rz = co[(size_t)r * 3 + 2];
      const float cx = co[(size_t)c * 3 + 0], cy = co[(size_t)c * 3 + 1],
                  cz = co[(size_t)c * 3 + 2];
      const float dx = rx - cx, dy = ry - cy, dz = rz - cz;
      f32x4 c4;
      c4[0] = dx; c4[1] = dy; c4[2] = dz; c4[3] = dx * dx + dy * dy + dz * dz;
      *reinterpret_cast<f32x4*>(&cdw[lane * 4]) = c4;
    }
    // prefetch next group's srt8
    {
      const int gn = grp + GS;
      if (lane < 32) {
        long e = (long)gn * 32 + lane;
        if (e >= E) e = E - 1;
        s8 = srt8[e];
      }
    }
    // fragment sources
    short8 Ar[2], Ac[2], Ae[2];
#pragma unroll
    for (int mt = 0; mt < 2; ++mt) {
      const int4 v = idxw[t + 16 * mt];
      Ar[mt] = *reinterpret_cast<const short8*>(nfb + (size_t)v.x * 32 + g * 8);
      Ac[mt] = *reinterpret_cast<const short8*>(nfb + (size_t)v.y * 32 + g * 8);
      short8 a = {};
      if (g < 2) {
        const f32x4 x0 = *reinterpret_cast<const f32x4*>(ea + (size_t)v.z * 16 + g * 8);
        const f32x4 x1 = *reinterpret_cast<const f32x4*>(ea + (size_t)v.z * 16 + g * 8 + 4);
#pragma unroll
        for (int j = 0; j < 4; ++j) {
          a[j] = (short)f2bf(x0[j]);
          a[4 + j] = (short)f2bf(x1[j]);
        }
      } else if (g == 2) {
        a[0] = (short)f2bf(cdw[(t + 16 * mt) * 4 + 3]);
      }
      Ae[mt] = a;
    }
    // ---- layer 1: acc = bSum + nf_r@WA + nf_c@WB + ea@Wea ----
    f32x4 acc[2][4];
#pragma unroll
    for (int mt = 0; mt < 2; ++mt)
#pragma unroll
      for (int nt = 0; nt < 4; ++nt) {
        f32x4 c;
        c[0] = bS_r[nt]; c[1] = bS_r[nt]; c[2] = bS_r[nt]; c[3] = bS_r[nt];
        acc[mt][nt] = c;
      }
#pragma unroll
    for (int nt = 0; nt < 4; ++nt) {
      const int n = t + 16 * nt;
      const short8 bwa = *reinterpret_cast<const short8*>(&S.WAt[n * 32 + g * 8]);
      const short8 bwb = *reinterpret_cast<const short8*>(&S.WBt[n * 32 + g * 8]);
      short8 be = {};
      if (g < 2)
        be = *reinterpret_cast<const short8*>(&S.WeaP[n * 24 + g * 8]);
      else if (g == 2)
        be[0] = (short)S.WeaP[n * 24 + 16];
#pragma unroll
      for (int mt = 0; mt < 2; ++mt) {
        acc[mt][nt] = __builtin_amdgcn_mfma_f32_16x16x32_bf16(Ar[mt], bwa, acc[mt][nt], 0, 0, 0);
        acc[mt][nt] = __builtin_amdgcn_mfma_f32_16x16x32_bf16(Ac[mt], bwb, acc[mt][nt], 0, 0, 0);
        acc[mt][nt] = __builtin_amdgcn_mfma_f32_16x16x32_bf16(Ae[mt], be, acc[mt][nt], 0, 0, 0);
      }
    }
    // relu -> t1 (swizzled bf16 store)
#pragma unroll
    for (int mt = 0; mt < 2; ++mt)
#pragma unroll
      for (int nt = 0; nt < 4; ++nt)
#pragma unroll
        for (int j = 0; j < 4; ++j) {
          const int row = g * 4 + j + 16 * mt, col = t + 16 * nt;
          *reinterpret_cast<unsigned short*>(
              xb + row * 128 + ((col * 2) ^ ((row & 7) << 4))) =
              f2bf(fmaxf(acc[mt][nt][j], 0.f));
        }
    // ---- layer 2: m = relu(t1 @ We2 + be2) ----
    short8 A2[2][2];
#pragma unroll
    for (int mt = 0; mt < 2; ++mt)
#pragma unroll
      for (int kt = 0; kt < 2; ++kt) {
        const int row = t + 16 * mt;
        A2[mt][kt] = *reinterpret_cast<const short8*>(
            xb + row * 128 + ((kt * 64 + g * 16) ^ ((row & 7) << 4)));
      }
    f32x4 m2[2][4];
#pragma unroll
    for (int mt = 0; mt < 2; ++mt)
#pragma unroll
      for (int nt = 0; nt < 4; ++nt) {
        const int n = t + 16 * nt;
        f32x4 c;
        c[0] = be2_r[nt]; c[1] = be2_r[nt]; c[2] = be2_r[nt]; c[3] = be2_r[nt];
#pragma unroll
        for (int kt = 0; kt < 2; ++kt) {
          const short8 b = *reinterpret_cast<const short8*>(
              reinterpret_cast<char*>(S.We2t) + n * 128 +
              ((kt * 64 + g * 16) ^ ((n & 7) << 4)));
          c = __builtin_amdgcn_mfma_f32_16x16x32_bf16(A2[mt][kt], b, c, 0, 0, 0);
        }
#pragma unroll
        for (int j = 0; j < 4; ++j) c[j] = fmaxf(c[j], 0.f);
        m2[mt][nt] = c;
      }
    // m -> x (swizzled)
#pragma unroll
    for (int mt = 0; mt < 2; ++mt)
#pragma unroll
      for (int nt = 0; nt < 4; ++nt)
#pragma unroll
        for (int j = 0; j < 4; ++j) {
          const int row = g * 4 + j + 16 * mt, col = t + 16 * nt;
          *reinterpret_cast<unsigned short*>(
              xb + row * 128 + ((col * 2) ^ ((row & 7) << 4))) =
              f2bf(m2[mt][nt][j]);
        }
    // ---- coord MLP: p = relu(m @ Wc1 + bc1); s = p.Wc2 + bc2 ----
    short8 A3[2][2];
#pragma unroll
    for (int mt = 0; mt < 2; ++mt)
#pragma unroll
      for (int kt = 0; kt < 2; ++kt) {
        const int row = t + 16 * mt;
        A3[mt][kt] = *reinterpret_cast<const short8*>(
            xb + row * 128 + ((kt * 64 + g * 16) ^ ((row & 7) << 4)));
      }
    float sv[2][4];
#pragma unroll
    for (int mt = 0; mt < 2; ++mt)
#pragma unroll
      for (int j = 0; j < 4; ++j) sv[mt][j] = 0.f;
#pragma unroll
    for (int mt = 0; mt < 2; ++mt)
#pragma unroll
      for (int nt = 0; nt < 4; ++nt) {
        const int n = t + 16 * nt;
        f32x4 c;
        c[0] = bc1_r[nt]; c[1] = bc1_r[nt]; c[2] = bc1_r[nt]; c[3] = bc1_r[nt];
#pragma unroll
        for (int kt = 0; kt < 2; ++kt) {
          const short8 b = *reinterpret_cast<const short8*>(
              reinterpret_cast<char*>(S.Wc1t) + n * 128 +
              ((kt * 64 + g * 16) ^ ((n & 7) << 4)));
          c = __builtin_amdgcn_mfma_f32_16x16x32_bf16(A3[mt][kt], b, c, 0, 0, 0);
        }
#pragma unroll
        for (int j = 0; j < 4; ++j) sv[mt][j] = fmaf(fmaxf(c[j], 0.f), wc2_r[nt], sv[mt][j]);
      }
#pragma unroll
    for (int d = 1; d < 16; d <<= 1)
#pragma unroll
      for (int mt = 0; mt < 2; ++mt)
#pragma unroll
        for (int j = 0; j < 4; ++j) sv[mt][j] += __shfl_xor(sv[mt][j], d, 64);
#pragma unroll
    for (int mt = 0; mt < 2; ++mt)
#pragma unroll
      for (int j = 0; j < 4; ++j) sv[mt][j] += bc2v;
    // stash s per row (radial slot; radial already consumed)
#pragma unroll
    for (int mt = 0; mt < 2; ++mt)
#pragma unroll
      for (int j = 0; j < 4; ++j)
        if (t == 0) cdw[(g * 4 + j + 16 * mt) * 4 + 3] = sv[mt][j];

    // ---- run-compressed agg_m (lane owns column `lane`) ----
    {
      float accm = 0.f;
#pragma unroll
      for (int r = 0; r < 32; ++r) {
        const int rIr = idxw[r].x;
        const bool valid = (e0 + r) < E;
        const float mv = bf2f(*reinterpret_cast<const unsigned short*>(
            xb + r * 128 + ((lane * 2) ^ ((r & 7) << 4))));
        if (valid) accm += mv;
        const bool closes = (r == 31) || ((e0 + r + 1) >= E) || (idxw[r + 1].x != rIr);
        if (valid && closes) {
          atomAddF(&agg_m[(size_t)rIr * 64 + lane], accm);
          accm = 0.f;
        }
      }
    }
    // ---- run-compressed agg_x (lanes 0..2) ----
    if (lane < 3) {
      float accx = 0.f;
#pragma unroll
      for (int r = 0; r < 32; ++r) {
        const int rIr = idxw[r].x;
        const bool valid = (e0 + r) < E;
        if (valid) accx += cdw[r * 4 + lane] * cdw[r * 4 + 3];
        const bool closes = (r == 31) || ((e0 + r + 1) >= E) || (idxw[r + 1].x != rIr);
        if (valid && closes) {
          atomAddF(&agg_x[(size_t)rIr * 3 + lane], accx);
          accx = 0.f;
        }
      }
    }
  }
}

// ---------------- k_node (MFMA, folded weights) ----------------
struct NodeLds {
  unsigned short Wn1bT[64 * 72];  // [n][k] stride 72 (agg-part of Wn1)
  unsigned short WnoT[64 * 72];   // [n][k] stride 72 (Wn2@W_out fold)
  unsigned short x[4][32 * 72];   // q tile
};

__global__ __launch_bounds__(256, 4) void k_node(
    const unsigned short* __restrict__ nfb, const float* __restrict__ agg_m,
    const float* __restrict__ agg_x, const int* __restrict__ deg,
    const float* __restrict__ co, const float* __restrict__ WF1,
    const float* __restrict__ Wn1, const float* __restrict__ Wno,
    const float* __restrict__ bn1f, const float* __restrict__ bno,
    float* __restrict__ out, float* __restrict__ co_out, int N) {
  __shared__ NodeLds S;
  const int tid = threadIdx.x;
  for (int i = tid; i < 4096; i += 256) {
    const int k = i >> 6, n = i & 63;
    S.Wn1bT[n * 72 + k] = f2bf(Wn1[(64 + k) * 64 + n]);
    S.WnoT[n * 72 + k] = f2bf(Wno[k * 64 + n]);
  }
  __syncthreads();
  const int w = tid >> 6, lane = tid & 63;
  const int g = lane >> 4, t = lane & 15;

  short8 fW1[4];
  float b1_r[4], bo_r[4];
#pragma unroll
  for (int nt = 0; nt < 4; ++nt) {
    const int n = t + 16 * nt;
    short8 a;
#pragma unroll
    for (int j = 0; j < 8; ++j) a[j] = (short)f2bf(WF1[(g * 8 + j) * 64 + n]);
    fW1[nt] = a;
    b1_r[nt] = bn1f[n];
    bo_r[nt] = bno[n];
  }

  unsigned short* xw = &S.x[w][0];
  const int ngroups = (N + 31) >> 5;
  const int GS = gridDim.x * 4;

  for (int grp = blockIdx.x * 4 + w; grp < ngroups; grp += GS) {
    const int base = grp * 32;
    short8 A1[2], Aa[2][2];
#pragma unroll
    for (int mt = 0; mt < 2; ++mt) {
      int node = base + t + 16 * mt;
      if (node >= N) node = N - 1;
      A1[mt] = *reinterpret_cast<const short8*>(nfb + (size_t)node * 32 + g * 8);
#pragma unroll
      for (int kt = 0; kt < 2; ++kt) {
        const f32x4 v0 = *reinterpret_cast<const f32x4*>(
            agg_m + (size_t)node * 64 + kt * 32 + g * 8);
        const f32x4 v1 = *reinterpret_cast<const f32x4*>(
            agg_m + (size_t)node * 64 + kt * 32 + g * 8 + 4);
        short8 a;
#pragma unroll
        for (int j = 0; j < 4; ++j) {
          a[j] = (short)f2bf(v0[j]);
          a[4 + j] = (short)f2bf(v1[j]);
        }
        Aa[mt][kt] = a;
      }
    }
    // layer 1
    f32x4 acc[2][4];
#pragma unroll
    for (int mt = 0; mt < 2; ++mt)
#pragma unroll
      for (int nt = 0; nt < 4; ++nt) {
        const int n = t + 16 * nt;
        f32x4 c;
        c[0] = b1_r[nt]; c[1] = b1_r[nt]; c[2] = b1_r[nt]; c[3] = b1_r[nt];
        c = __builtin_amdgcn_mfma_f32_16x16x32_bf16(A1[mt], fW1[nt], c, 0, 0, 0);
#pragma unroll
        for (int kt = 0; kt < 2; ++kt) {
          const short8 b = *reinterpret_cast<const short8*>(
              &S.Wn1bT[n * 72 + kt * 32 + g * 8]);
          c = __builtin_amdgcn_mfma_f32_16x16x32_bf16(Aa[mt][kt], b, c, 0, 0, 0);
        }
        acc[mt][nt] = c;
      }
    // relu -> q
#pragma unroll
    for (int mt = 0; mt < 2; ++mt)
#pragma unroll
      for (int nt = 0; nt < 4; ++nt)
#pragma unroll
        for (int j = 0; j < 4; ++j)
          xw[(g * 4 + j + 16 * mt) * 72 + t + 16 * nt] =
              f2bf(fmaxf(acc[mt][nt][j], 0.f));
    // layer 2 (folded) -> out
    short8 A2[2][2];
#pragma unroll
    for (int mt = 0; mt < 2; ++mt)
#pragma unroll
      for (int kt = 0; kt < 2; ++kt)
        A2[mt][kt] = *reinterpret_cast<const short8*>(
            &S.x[w][(t + 16 * mt) * 72 + kt * 32 + g * 8]);
#pragma unroll
    for (int mt = 0; mt < 2; ++mt)
#pragma unroll
      for (int nt = 0; nt < 4; ++nt) {
        const int n = t + 16 * nt;
        f32x4 c;
        c[0] = bo_r[nt]; c[1] = bo_r[nt]; c[2] = bo_r[nt]; c[3] = bo_r[nt];
#pragma unroll
        for (int kt = 0; kt < 2; ++kt) {
          const short8 b = *reinterpret_cast<const short8*>(
              &S.WnoT[n * 72 + kt * 32 + g * 8]);
          c = __builtin_amdgcn_mfma_f32_16x16x32_bf16(A2[mt][kt], b, c, 0, 0, 0);
        }
#pragma unroll
        for (int j = 0; j < 4; ++j) {
          const int node = base + g * 4 + j + 16 * mt;
          if (node < N) out[(size_t)node * 64 + n] = c[j];
        }
      }
    // coords update
    if (lane < 32) {
      const int node = base + lane;
      if (node < N) {
        const float dv = fmaxf((float)deg[node], 1.f);
#pragma unroll
        for (int d = 0; d < 3; ++d)
          co_out[(size_t)node * 3 + d] =
              co[(size_t)node * 3 + d] + agg_x[(size_t)node * 3 + d] / dv;
      }
    }
  }
}

extern "C" void kernel_launch(void* const* d_in, const int* in_sizes, int n_in,
                              void* d_out, int out_size, void* d_ws, size_t ws_size,
                              hipStream_t stream) {
  const float* nf = (const float*)d_in[0];
  const float* ea = (const float*)d_in[1];
  const float* co = (const float*)d_in[2];
  const int* ei = (const int*)d_in[3];
  const float* W_in = (const float*)d_in[4];
  const float* b_in = (const float*)d_in[5];
  const float* W_out = (const float*)d_in[6];
  const float* b_out = (const float*)d_in[7];
  const float* We1 = (const float*)d_in[8];
  const float* be1 = (const float*)d_in[9];
  const float* We2 = (const float*)d_in[10];
  const float* be2 = (const float*)d_in[11];
  const float* Wn1 = (const float*)d_in[12];
  const float* bn1 = (const float*)d_in[13];
  const float* Wn2 = (const float*)d_in[14];
  const float* bn2 = (const float*)d_in[15];
  const float* Wc1 = (const float*)d_in[16];
  const float* bc1 = (const float*)d_in[17];
  const float* Wc2 = (const float*)d_in[18];
  const float* bc2 = (const float*)d_in[19];

  const int N = in_sizes[0] / 32;
  const int E = in_sizes[1] / 16;

  float* ws = (float*)d_ws;
  float* agg_m = ws;                                   // N*64
  float* agg_x = agg_m + (size_t)N * 64;               // N*3
  int* deg = (int*)(agg_x + (size_t)N * 3);            // N
  float* WA = (float*)(deg + N);                       // 2048
  float* WB = WA + 2048;
  float* WF1 = WB + 2048;
  float* Wno = WF1 + 2048;                             // 4096
  float* bSum = Wno + 4096;                            // 64
  float* bn1f = bSum + 64;
  float* bno = bn1f + 64;
  int* rowNext = (int*)(bno + 64);                     // N
  int* bsumBuf = rowNext + N;                          // 512
  uintptr_t pp = (uintptr_t)(bsumBuf + 512);
  pp = (pp + 7) & ~(uintptr_t)7;
  unsigned long long* srt8 = (unsigned long long*)pp;  // E
  unsigned short* nfb = (unsigned short*)(srt8 + E);   // N*32

  float* outp = (float*)d_out;
  float* co_out = outp + (size_t)N * 64;

  const int nb = (N + 255) / 256;

  k_prep<<<1031, 256, 0, stream>>>(nf, W_in, b_in, We1, be1, Wn1, bn1, Wn2,
                                   bn2, W_out, b_out, nfb, WA, WB, WF1, Wno,
                                   bSum, bn1f, bno, agg_m, N);
  k_hist<<<512, 256, 0, stream>>>(ei, deg, E);
  k_scanA<<<nb, 256, 0, stream>>>(deg, rowNext, bsumBuf, N);
  k_scanC<<<nb, 256, 0, stream>>>(rowNext, bsumBuf, N);
  k_scatter<<<512, 256, 0, stream>>>(ei, rowNext, srt8, E);
  k_edge<<<768, 256, 0, stream>>>(nfb, ea, co, srt8, We1, WA, WB, bSum, be2,
                                  We2, bc1, Wc1, Wc2, bc2, agg_m, agg_x, E);
  k_node<<<512, 256, 0, stream>>>(nfb, agg_m, agg_x, deg, co, WF1, Wn1, Wno,
                                  bn1f, bno, outp, co_out, N);
}